// Round 2
// 511.781 us; speedup vs baseline: 1.0392x; 1.0392x over previous
//
#include <hip/hip_runtime.h>

// ---------- problem constants ----------
#define HW_   576
#define BHW   1152      // B*HW
#define DD    2048
#define CLIPC 1024
#define NSEQ  768
#define LL    25
#define KPAD  640       // clip-gemm K (588) padded to a multiple of 64

// fp8 pre-scaling: A stored as 8*x, B stored as 32*w  ->  acc = 256 * true
#define ASCALE 8.0f
#define BSCALE 32.0f
#define INV_AB (1.0f/256.0f)

typedef __bf16 bf16x8 __attribute__((ext_vector_type(8)));
typedef float  f32x4  __attribute__((ext_vector_type(4)));
typedef int    i32x8  __attribute__((ext_vector_type(8)));
typedef unsigned short u16;
typedef unsigned char  u8;

__device__ __forceinline__ float bf2f(u16 u){
  union { unsigned int i; float f; } v; v.i = ((unsigned int)u) << 16; return v.f;
}
__device__ __forceinline__ u16 f2bf(float f){
  union { float f; unsigned int i; } v; v.f = f;
  unsigned int u = v.i;
  return (u16)((u + 0x7fffu + ((u >> 16) & 1u)) >> 16);  // RNE
}
__device__ __forceinline__ unsigned int pk2bf(float a, float b){
  return ((unsigned int)f2bf(a)) | (((unsigned int)f2bf(b)) << 16);
}
__device__ __forceinline__ unsigned int pk4_fp8(float a, float b, float c, float d){
  int v = 0;
  v = __builtin_amdgcn_cvt_pk_fp8_f32(a, b, v, false);
  v = __builtin_amdgcn_cvt_pk_fp8_f32(c, d, v, true);
  return (unsigned int)v;
}

// async global->LDS, 16B per lane; LDS dest = wave-uniform base + lane*16
__device__ __forceinline__ void gld_lds16(const void* g, void* l){
  __builtin_amdgcn_global_load_lds((__attribute__((address_space(1))) void*)g,
                                   (__attribute__((address_space(3))) void*)l,
                                   16, 0, 0);
}

// ---------- fused prep (launch 1 of 4) ----------
// [0,7168): norm_w -> fp8 x32 (B8)      [7168,8192): input_w -> bf16 (inpw)
// [8192,8704): output_w -> bf16 (outw)  [8704,9728): clipw pad (+blk8704: zero rowacc/counter)
// [9728,10880): patchify               [10880,20096): gather+LN (idx computed inline)
__global__ void prep_k(const float* __restrict__ norm_w, const float* __restrict__ input_w,
                       const float* __restrict__ output_w, const float* __restrict__ clip_w,
                       const float* __restrict__ images, const float* __restrict__ feats,
                       const int* __restrict__ ids,
                       const float* __restrict__ gamma, const float* __restrict__ beta,
                       u8* __restrict__ B8, u16* __restrict__ inpw, u16* __restrict__ outw,
                       u16* __restrict__ clipw, u16* __restrict__ patch,
                       u8* __restrict__ A8, u16* __restrict__ A7,
                       float* __restrict__ rowacc, unsigned int* __restrict__ done){
  const int blk = blockIdx.x, tid = threadIdx.x;
  if (blk < 7168){
    long idx = (long)blk*2048 + tid*8;
    float4 v0 = *(const float4*)(norm_w + idx);
    float4 v1 = *(const float4*)(norm_w + idx + 4);
    uint2 o;
    o.x = pk4_fp8(v0.x*BSCALE, v0.y*BSCALE, v0.z*BSCALE, v0.w*BSCALE);
    o.y = pk4_fp8(v1.x*BSCALE, v1.y*BSCALE, v1.z*BSCALE, v1.w*BSCALE);
    *(uint2*)(B8 + idx) = o;
    return;
  }
  if (blk < 8704){
    const bool isInp = (blk < 8192);
    long idx = (long)(blk - (isInp ? 7168 : 8192))*2048 + tid*8;
    const float* s = isInp ? (input_w + idx) : (output_w + idx);
    float4 v0 = *(const float4*)s;
    float4 v1 = *(const float4*)(s + 4);
    uint4 o = { pk2bf(v0.x,v0.y), pk2bf(v0.z,v0.w), pk2bf(v1.x,v1.y), pk2bf(v1.z,v1.w) };
    *(uint4*)((isInp ? inpw : outw) + idx) = o;
    return;
  }
  if (blk < 9728){
    const int c = blk - 8704;
    for (int k = tid; k < KPAD; k += 256)
      clipw[c*KPAD + k] = (k < 588) ? f2bf(clip_w[c*588 + k]) : (u16)0;
    if (blk == 8704){
      for (int i = tid; i < BHW*4; i += 256) rowacc[i] = 0.f;
      if (tid == 0) *done = 0u;
    }
    return;
  }
  if (blk < 10880){
    const int r = blk - 9728;
    const int b = r / HW_, n = r % HW_;
    const int hi = n / 24, wi = n % 24;
    for (int p = tid; p < KPAD; p += 256){
      float v = 0.f;
      if (p < 588){
        int c3 = p / 196, rem = p - c3*196;
        int ph = rem / 14, pw = rem - ph*14;
        v = images[(((long)b*4 + c3)*336 + hi*14 + ph)*336 + wi*14 + pw];
      }
      patch[(long)r*KPAD + p] = f2bf(v);
    }
    return;
  }
  // gather + LayerNorm (image-token index computed inline; ids rows are L2-resident)
  const int q = blk - 10880;
  const int r = q >> 3, g = q & 7;
  const int b = r / HW_, n = r % HW_;
  const int hi = n / 24, wi = n % 24;
  __shared__ int ridx[4];
  __shared__ float rs[4], rq[4];
  {
    int best = 0x7fffffff;
    for (int i = tid; i < NSEQ; i += 256)
      if (ids[b*NSEQ + i] == -200 && i < best) best = i;
    for (int off = 32; off; off >>= 1){ int o = __shfl_xor(best, off); best = min(best, o); }
    if ((tid & 63) == 0) ridx[tid >> 6] = best;
    __syncthreads();
  }
  const int tok = min(min(ridx[0],ridx[1]),min(ridx[2],ridx[3])) + 1 + hi*25 + wi;
  const int layer = (g < 7) ? (24 - g*4) : 24;
  const float* src = feats + (((long)(b*NSEQ + tok))*LL + layer)*DD + tid*8;
  float4 a = *(const float4*)src;
  float4 c = *(const float4*)(src + 4);
  if (g == 7){
    uint4 o = { pk2bf(a.x,a.y), pk2bf(a.z,a.w), pk2bf(c.x,c.y), pk2bf(c.z,c.w) };
    *(uint4*)(A7 + (long)r*DD + tid*8) = o;
    return;
  }
  float s  = a.x+a.y+a.z+a.w + c.x+c.y+c.z+c.w;
  float qq = a.x*a.x+a.y*a.y+a.z*a.z+a.w*a.w + c.x*c.x+c.y*c.y+c.z*c.z+c.w*c.w;
  for (int off = 32; off; off >>= 1){ s += __shfl_xor(s, off); qq += __shfl_xor(qq, off); }
  const int wave = tid >> 6, lane = tid & 63;
  if (lane == 0){ rs[wave] = s; rq[wave] = qq; }
  __syncthreads();
  const float ts = rs[0]+rs[1]+rs[2]+rs[3];
  const float tq = rq[0]+rq[1]+rq[2]+rq[3];
  const float mu   = ts * (1.f/2048.f);
  const float var  = tq * (1.f/2048.f) - mu*mu;
  const float rstd = rsqrtf(var + 1e-5f);
  const float4 g0 = *(const float4*)(gamma + g*DD + tid*8);
  const float4 g1 = *(const float4*)(gamma + g*DD + tid*8 + 4);
  const float4 b0 = *(const float4*)(beta  + g*DD + tid*8);
  const float4 b1 = *(const float4*)(beta  + g*DD + tid*8 + 4);
  uint2 o;
  o.x = pk4_fp8(((a.x-mu)*rstd*g0.x + b0.x)*ASCALE, ((a.y-mu)*rstd*g0.y + b0.y)*ASCALE,
                ((a.z-mu)*rstd*g0.z + b0.z)*ASCALE, ((a.w-mu)*rstd*g0.w + b0.w)*ASCALE);
  o.y = pk4_fp8(((c.x-mu)*rstd*g1.x + b1.x)*ASCALE, ((c.y-mu)*rstd*g1.y + b1.y)*ASCALE,
                ((c.z-mu)*rstd*g1.z + b1.z)*ASCALE, ((c.w-mu)*rstd*g1.w + b1.w)*ASCALE);
  *(uint2*)(A8 + ((long)g*BHW + r)*DD + tid*8) = o;
}

// ---------- unified GEMM (launch 2 of 4): z=0..6 fp8 vis; z=7 inp bf16; z=8 clip bf16->fp32 ----------
// 1D grid of 648 blocks; flat%8 == z for z<8 so each XCD's L2 holds ONE z-slice
// (A8_z + B8_z ~ 4.5 MB vs 4 MiB L2; round-robin dispatch puts flat%8 on XCD flat%8).
__global__ __launch_bounds__(256, 3)
void gemm9_k(const u8* __restrict__ A8, const u8* __restrict__ B8,
             u16* __restrict__ C_all, const u16* __restrict__ A7,
             const u16* __restrict__ inpw, const u16* __restrict__ patch,
             const u16* __restrict__ clipw, float* __restrict__ cf,
             const float* __restrict__ input_b, const float* __restrict__ clip_b){
  __shared__ alignas(16) u8 smem[32768];
  const int f = blockIdx.x;
  int z, t;
  if (f < 576){ z = f & 7; t = f >> 3; } else { z = 8; t = f - 576; }
  const int bm = (t % 9)*128, bn = (t / 9)*128;
  const int tid = threadIdx.x, wave = tid >> 6, lane = tid & 63;
  const int l15 = lane & 15, quad = lane >> 4;
  const int wr = (wave >> 1)*64, wc = (wave & 1)*64;
  f32x4 acc[4][4] = {};
  const int laneRow   = lane >> 3;
  const int laneChunk = (lane & 7) ^ laneRow;

  if (z < 7){
    // ---- MX-fp8, BK=128, XOR-16B-chunk swizzle, identity E8M0 scales ----
    u8* As = smem;
    u8* Bs = smem + 16384;
    const u8* Az = A8 + (long)z*BHW*DD;
    const u8* Bz = B8 + (long)z*CLIPC*DD;
    const u8* gA = Az + (long)(bm + wave*32 + laneRow)*DD + laneChunk*16;
    const u8* gB = Bz + (long)(bn + wave*32 + laneRow)*DD + laneChunk*16;
    u8* lA = &As[wave*32*128];
    u8* lB = &Bs[wave*32*128];
    const long rs8 = 8L*DD;
    for (int k0 = 0; k0 < DD; k0 += 128){
#pragma unroll
      for (int t2 = 0; t2 < 4; t2++) gld_lds16(gA + k0 + t2*rs8, lA + t2*1024);
#pragma unroll
      for (int t2 = 0; t2 < 4; t2++) gld_lds16(gB + k0 + t2*rs8, lB + t2*1024);
      __syncthreads();
      i32x8 af[4], bg[4];
      const int sw = l15 & 7;
#pragma unroll
      for (int i = 0; i < 4; i++){
        const u8* rp = &As[(wr + i*16 + l15)*128];
        uint4 lo = *(const uint4*)(rp + (((quad*2 + 0) ^ sw)*16));
        uint4 hi = *(const uint4*)(rp + (((quad*2 + 1) ^ sw)*16));
        af[i] = (i32x8){(int)lo.x,(int)lo.y,(int)lo.z,(int)lo.w,
                        (int)hi.x,(int)hi.y,(int)hi.z,(int)hi.w};
      }
#pragma unroll
      for (int j = 0; j < 4; j++){
        const u8* rp = &Bs[(wc + j*16 + l15)*128];
        uint4 lo = *(const uint4*)(rp + (((quad*2 + 0) ^ sw)*16));
        uint4 hi = *(const uint4*)(rp + (((quad*2 + 1) ^ sw)*16));
        bg[j] = (i32x8){(int)lo.x,(int)lo.y,(int)lo.z,(int)lo.w,
                        (int)hi.x,(int)hi.y,(int)hi.z,(int)hi.w};
      }
#pragma unroll
      for (int i = 0; i < 4; i++)
#pragma unroll
        for (int j = 0; j < 4; j++)
          acc[i][j] = __builtin_amdgcn_mfma_scale_f32_16x16x128_f8f6f4(
              af[i], bg[j], acc[i][j], 0, 0, 0, 0x7F7F7F7F, 0, 0x7F7F7F7F);
      __syncthreads();
    }
    u16* C = C_all + (long)z*BHW*CLIPC;
#pragma unroll
    for (int i = 0; i < 4; i++)
#pragma unroll
      for (int j = 0; j < 4; j++)
#pragma unroll
        for (int rr = 0; rr < 4; rr++){
          const int row = bm + wr + i*16 + quad*4 + rr;
          const int col = bn + wc + j*16 + l15;
          C[(long)row*CLIPC + col] = f2bf(acc[i][j][rr] * INV_AB);
        }
  } else {
    // ---- bf16, BK=64, XOR swizzle ----
    u16* As = (u16*)smem;
    u16* Bs = (u16*)(smem + 16384);
    const u16* Az = (z == 7) ? A7   : patch;
    const u16* Bz = (z == 7) ? inpw : clipw;
    const int K  = (z == 7) ? DD : KPAD;
    const int laneCol = laneChunk * 8;
    const u16* gA = Az + (long)(bm + wave*32 + laneRow)*K + laneCol;
    const u16* gB = Bz + (long)(bn + wave*32 + laneRow)*K + laneCol;
    u16* lA = &As[wave*2048];
    u16* lB = &Bs[wave*2048];
    const long rs8 = (long)8 * K;
    for (int k0 = 0; k0 < K; k0 += 64){
#pragma unroll
      for (int t2 = 0; t2 < 4; t2++) gld_lds16(gA + k0 + t2*rs8, lA + t2*512);
#pragma unroll
      for (int t2 = 0; t2 < 4; t2++) gld_lds16(gB + k0 + t2*rs8, lB + t2*512);
      __syncthreads();
#pragma unroll
      for (int s = 0; s < 2; s++){
        bf16x8 af[4], bg[4];
#pragma unroll
        for (int i = 0; i < 4; i++)
          af[i] = *(const bf16x8*)&As[(wr + i*16 + l15)*64 + (((s*4 + quad) ^ (l15 & 7))*8)];
#pragma unroll
        for (int j = 0; j < 4; j++)
          bg[j] = *(const bf16x8*)&Bs[(wc + j*16 + l15)*64 + (((s*4 + quad) ^ (l15 & 7))*8)];
#pragma unroll
        for (int i = 0; i < 4; i++)
#pragma unroll
          for (int j = 0; j < 4; j++)
            acc[i][j] = __builtin_amdgcn_mfma_f32_16x16x32_bf16(af[i], bg[j], acc[i][j], 0, 0, 0);
      }
      __syncthreads();
    }
    if (z == 7){
      u16* C = C_all + 7L*BHW*CLIPC;
#pragma unroll
      for (int i = 0; i < 4; i++)
#pragma unroll
        for (int j = 0; j < 4; j++)
#pragma unroll
          for (int rr = 0; rr < 4; rr++){
            const int row = bm + wr + i*16 + quad*4 + rr;
            const int col = bn + wc + j*16 + l15;
            C[(long)row*CLIPC + col] = f2bf(acc[i][j][rr] + input_b[col]);
          }
    } else {
#pragma unroll
      for (int i = 0; i < 4; i++)
#pragma unroll
        for (int j = 0; j < 4; j++)
#pragma unroll
          for (int rr = 0; rr < 4; rr++){
            const int row = bm + wr + i*16 + quad*4 + rr;
            const int col = bn + wc + j*16 + l15;
            cf[(long)row*CLIPC + col] = acc[i][j][rr] + clip_b[col];
          }
    }
  }
}

// ---------- attention (launch 3 of 4): 256 threads = 4 heads ----------
__global__ void attn_k(const u16* __restrict__ C_all, u16* __restrict__ fuse){
  const int r = blockIdx.x;
  const int h = (blockIdx.y << 2) | (threadIdx.x >> 6);
  const int lane = threadIdx.x & 63;
  const long slot = (long)BHW * CLIPC;
  const long rb = (long)r * CLIPC;
  const int c0 = h*128 + lane, c1 = c0 + 64;
  const float q0 = bf2f(C_all[rb + c0]), q1 = bf2f(C_all[rb + c1]);
  float k0v[6], k1v[6], dt[6];
#pragma unroll
  for (int t = 0; t < 6; t++){
    const u16* base = C_all + (long)(t+1)*slot + rb;
    k0v[t] = bf2f(base[c0]); k1v[t] = bf2f(base[c1]);
    dt[t] = q0*k0v[t] + q1*k1v[t];
  }
#pragma unroll
  for (int t = 0; t < 6; t++)
    for (int off = 32; off; off >>= 1) dt[t] += __shfl_xor(dt[t], off);
  float l[6], e[6];
#pragma unroll
  for (int t = 0; t < 6; t++) l[t] = dt[t] * 0.03125f;
  float m = l[0];
#pragma unroll
  for (int t = 1; t < 6; t++) m = fmaxf(m, l[t]);
  float ssum = 0.f;
#pragma unroll
  for (int t = 0; t < 6; t++){ e[t] = __expf(l[t] - m); ssum += e[t]; }
  const float inv = 1.f / ssum;
  float f0 = 0.f, f1 = 0.f;
#pragma unroll
  for (int t = 0; t < 6; t++){ const float a = e[t]*inv; f0 += a*k0v[t]; f1 += a*k1v[t]; }
  fuse[rb + c0] = f2bf(f0);
  fuse[rb + c1] = f2bf(f1);
}

// ---------- output GEMM + cosine partials + last-block final loss (launch 4 of 4) ----------
// Only 72 blocks -> 1 block/CU -> no cross-block TLP to hide staging latency.
// Double-buffered LDS (64 KB): issue next K-chunk's global_load_lds BEFORE computing
// the current one; __syncthreads' vmcnt(0) drain then overlaps the MFMA phase.
__global__ __launch_bounds__(256, 2)
void gemm_out_k(const u16* __restrict__ fuse, const u16* __restrict__ outw,
                const u16* __restrict__ inp, const float* __restrict__ output_b,
                const float* __restrict__ cf, float* __restrict__ rowacc,
                unsigned int* __restrict__ done, float* __restrict__ out){
  __shared__ alignas(16) u8 smem[65536];
  const int bm = blockIdx.x*128, bn = blockIdx.y*128;
  const int tid = threadIdx.x, wave = tid >> 6, lane = tid & 63;
  const int l15 = lane & 15, quad = lane >> 4;
  const int wr = (wave >> 1)*64, wc = (wave & 1)*64;
  f32x4 acc[4][4] = {};
  {
    const int laneRow = lane >> 3;
    const int laneCol = (((lane & 7) ^ laneRow) * 8);
    const u16* gA = fuse + (long)(bm + wave*32 + laneRow)*CLIPC + laneCol;
    const u16* gB = outw + (long)(bn + wave*32 + laneRow)*CLIPC + laneCol;
    const long rs8 = 8L*CLIPC;
    // prologue: stage k0=0 into buffer 0
#pragma unroll
    for (int t = 0; t < 4; t++) gld_lds16(gA + t*rs8, (u16*)smem + wave*2048 + t*512);
#pragma unroll
    for (int t = 0; t < 4; t++) gld_lds16(gB + t*rs8, (u16*)(smem + 16384) + wave*2048 + t*512);
    __syncthreads();
    for (int k0 = 0; k0 < CLIPC; k0 += 64){
      const int cur = (k0 >> 6) & 1;
      if (k0 + 64 < CLIPC){
        u16* lA = (u16*)(smem + (cur^1)*32768)         + wave*2048;
        u16* lB = (u16*)(smem + (cur^1)*32768 + 16384) + wave*2048;
#pragma unroll
        for (int t = 0; t < 4; t++) gld_lds16(gA + (k0+64) + t*rs8, lA + t*512);
#pragma unroll
        for (int t = 0; t < 4; t++) gld_lds16(gB + (k0+64) + t*rs8, lB + t*512);
      }
      const u16* As = (const u16*)(smem + cur*32768);
      const u16* Bs = (const u16*)(smem + cur*32768 + 16384);
#pragma unroll
      for (int s = 0; s < 2; s++){
        bf16x8 af[4], bg[4];
#pragma unroll
        for (int i = 0; i < 4; i++)
          af[i] = *(const bf16x8*)&As[(wr + i*16 + l15)*64 + (((s*4 + quad) ^ (l15 & 7))*8)];
#pragma unroll
        for (int j = 0; j < 4; j++)
          bg[j] = *(const bf16x8*)&Bs[(wc + j*16 + l15)*64 + (((s*4 + quad) ^ (l15 & 7))*8)];
#pragma unroll
        for (int i = 0; i < 4; i++)
#pragma unroll
          for (int j = 0; j < 4; j++)
            acc[i][j] = __builtin_amdgcn_mfma_f32_16x16x32_bf16(af[i], bg[j], acc[i][j], 0, 0, 0);
      }
      __syncthreads();   // drains vmcnt(0): next buffer's staging completes under this iter's MFMAs
    }
  }
#pragma unroll
  for (int i = 0; i < 4; i++)
#pragma unroll
    for (int rr = 0; rr < 4; rr++){
      const int row = bm + wr + i*16 + quad*4 + rr;
      float soc = 0.f, soo = 0.f, scc = 0.f;
#pragma unroll
      for (int j = 0; j < 4; j++){
        const int col = bn + wc + j*16 + l15;
        const long p = (long)row*CLIPC + col;
        const float o = acc[i][j][rr] + output_b[col] + bf2f(inp[p]);
        const float c = cf[p];
        soc += o*c; soo += o*o; scc += c*c;
      }
#pragma unroll
      for (int off = 1; off < 16; off <<= 1){
        soc += __shfl_xor(soc, off); soo += __shfl_xor(soo, off); scc += __shfl_xor(scc, off);
      }
      if (l15 == 0){
        atomicAdd(&rowacc[row*4 + 0], soc);
        atomicAdd(&rowacc[row*4 + 1], soo);
        atomicAdd(&rowacc[row*4 + 2], scc);
      }
    }
  // ---- last block computes the final loss ----
  __threadfence();
  __shared__ unsigned int amLast;
  if (tid == 0) amLast = (atomicAdd(done, 1u) == 71u) ? 1u : 0u;
  __syncthreads();
  if (!amLast) return;
  float s = 0.f;
  for (int r = tid; r < BHW; r += 256){
    const float soc = __hip_atomic_load(&rowacc[r*4+0], __ATOMIC_RELAXED, __HIP_MEMORY_SCOPE_AGENT);
    const float soo = __hip_atomic_load(&rowacc[r*4+1], __ATOMIC_RELAXED, __HIP_MEMORY_SCOPE_AGENT);
    const float scc = __hip_atomic_load(&rowacc[r*4+2], __ATOMIC_RELAXED, __HIP_MEMORY_SCOPE_AGENT);
    s += soc / fmaxf(sqrtf(soo*scc), 1e-8f);
  }
  for (int off = 32; off; off >>= 1) s += __shfl_xor(s, off);
  __shared__ float fr[4];
  if ((tid & 63) == 0) fr[tid >> 6] = s;
  __syncthreads();
  if (tid == 0) out[0] = 1.f - (fr[0]+fr[1]+fr[2]+fr[3]) * (1.f/(float)BHW);
}

extern "C" void kernel_launch(void* const* d_in, const int* in_sizes, int n_in,
                              void* d_out, int out_size, void* d_ws, size_t ws_size,
                              hipStream_t stream){
  const int*   input_ids = (const int*)  d_in[0];
  const float* images    = (const float*)d_in[1];
  const float* all_feats = (const float*)d_in[2];
  const float* norm_gamma = (const float*)d_in[4];
  const float* norm_beta  = (const float*)d_in[5];
  const float* norm_w     = (const float*)d_in[6];
  const float* input_w    = (const float*)d_in[7];
  const float* input_b    = (const float*)d_in[8];
  const float* output_w   = (const float*)d_in[9];
  const float* output_b   = (const float*)d_in[10];
  const float* clip_w     = (const float*)d_in[11];
  const float* clip_b     = (const float*)d_in[12];
  float* out = (float*)d_out;

  // ---- workspace layout (~75 MB) ----
  char* w = (char*)d_ws;
  unsigned int* done = (unsigned int*)w;
  size_t off = 256;
  u8*  A8    = (u8*) (w + off); off += 7L*BHW*DD;
  u16* A7    = (u16*)(w + off); off += (long)BHW*DD*2;
  u8*  B8    = (u8*) (w + off); off += 7L*CLIPC*DD;
  u16* inpw  = (u16*)(w + off); off += (long)CLIPC*DD*2;
  u16* outw  = (u16*)(w + off); off += (long)CLIPC*CLIPC*2;
  u16* clipw = (u16*)(w + off); off += (long)CLIPC*KPAD*2;
  u16* patch = (u16*)(w + off); off += (long)BHW*KPAD*2;
  u16* C_all = (u16*)(w + off); off += 8L*BHW*CLIPC*2;
  u16* fuse  = (u16*)(w + off); off += (long)BHW*CLIPC*2;
  float* cf     = (float*)(w + off); off += (long)BHW*CLIPC*4;
  float* rowacc = (float*)(w + off); off += (long)BHW*4*4;

  prep_k<<<20096, 256, 0, stream>>>(norm_w, input_w, output_w, clip_w, images, all_feats,
                                    input_ids, norm_gamma, norm_beta,
                                    B8, inpw, outw, clipw, patch, A8, A7, rowacc, done);
  gemm9_k<<<648, 256, 0, stream>>>(A8, B8, C_all, A7, inpw, patch, clipw, cf,
                                   input_b, clip_b);
  attn_k<<<dim3(1152, 2), 256, 0, stream>>>(C_all, fuse);
  gemm_out_k<<<dim3(9, 8), 256, 0, stream>>>(fuse, outw, C_all + 7L*BHW*CLIPC,
                                             output_b, cf, rowacc, done, out);
}

// Round 3
// 496.092 us; speedup vs baseline: 1.0721x; 1.0316x over previous
//
#include <hip/hip_runtime.h>

// ---------- problem constants ----------
#define HW_   576
#define BHW   1152      // B*HW
#define DD    2048
#define CLIPC 1024
#define NSEQ  768
#define LL    25
#define KPAD  640       // clip-gemm K (588) padded to a multiple of 64

// fp8 pre-scaling: A stored as 8*x, B stored as 32*w  ->  acc = 256 * true
#define ASCALE 8.0f
#define BSCALE 32.0f
#define INV_AB (1.0f/256.0f)

typedef __bf16 bf16x8 __attribute__((ext_vector_type(8)));
typedef float  f32x4  __attribute__((ext_vector_type(4)));
typedef int    i32x8  __attribute__((ext_vector_type(8)));
typedef unsigned short u16;
typedef unsigned char  u8;

__device__ __forceinline__ float bf2f(u16 u){
  union { unsigned int i; float f; } v; v.i = ((unsigned int)u) << 16; return v.f;
}
__device__ __forceinline__ u16 f2bf(float f){
  union { float f; unsigned int i; } v; v.f = f;
  unsigned int u = v.i;
  return (u16)((u + 0x7fffu + ((u >> 16) & 1u)) >> 16);  // RNE
}
__device__ __forceinline__ unsigned int pk2bf(float a, float b){
  return ((unsigned int)f2bf(a)) | (((unsigned int)f2bf(b)) << 16);
}
__device__ __forceinline__ unsigned int pk4_fp8(float a, float b, float c, float d){
  int v = 0;
  v = __builtin_amdgcn_cvt_pk_fp8_f32(a, b, v, false);
  v = __builtin_amdgcn_cvt_pk_fp8_f32(c, d, v, true);
  return (unsigned int)v;
}

// async global->LDS, 16B per lane; LDS dest = wave-uniform base + lane*16
__device__ __forceinline__ void gld_lds16(const void* g, void* l){
  __builtin_amdgcn_global_load_lds((__attribute__((address_space(1))) void*)g,
                                   (__attribute__((address_space(3))) void*)l,
                                   16, 0, 0);
}

// ---------- fused prep (launch 1 of 4) ----------
// [0,8192): {norm_w | input_w} -> fp8 x32 (B8 slices 0..7)
// [8192,8704): output_w -> bf16 (outw)  [8704,9728): clipw pad (+blk8704: zero rowacc/counter)
// [9728,10880): patchify               [10880,20096): gather; g<7 LN->fp8, g==7 raw->fp8
__global__ void prep_k(const float* __restrict__ norm_w, const float* __restrict__ input_w,
                       const float* __restrict__ output_w, const float* __restrict__ clip_w,
                       const float* __restrict__ images, const float* __restrict__ feats,
                       const int* __restrict__ ids,
                       const float* __restrict__ gamma, const float* __restrict__ beta,
                       u8* __restrict__ B8, u16* __restrict__ outw,
                       u16* __restrict__ clipw, u16* __restrict__ patch,
                       u8* __restrict__ A8,
                       float* __restrict__ rowacc, unsigned int* __restrict__ done){
  const int blk = blockIdx.x, tid = threadIdx.x;
  if (blk < 8192){
    long idx = (long)blk*2048 + tid*8;
    const float* s = (blk < 7168) ? (norm_w + idx) : (input_w + (idx - 7168L*2048));
    float4 v0 = *(const float4*)s;
    float4 v1 = *(const float4*)(s + 4);
    uint2 o;
    o.x = pk4_fp8(v0.x*BSCALE, v0.y*BSCALE, v0.z*BSCALE, v0.w*BSCALE);
    o.y = pk4_fp8(v1.x*BSCALE, v1.y*BSCALE, v1.z*BSCALE, v1.w*BSCALE);
    *(uint2*)(B8 + idx) = o;
    return;
  }
  if (blk < 8704){
    long idx = (long)(blk - 8192)*2048 + tid*8;
    float4 v0 = *(const float4*)(output_w + idx);
    float4 v1 = *(const float4*)(output_w + idx + 4);
    uint4 o = { pk2bf(v0.x,v0.y), pk2bf(v0.z,v0.w), pk2bf(v1.x,v1.y), pk2bf(v1.z,v1.w) };
    *(uint4*)(outw + idx) = o;
    return;
  }
  if (blk < 9728){
    const int c = blk - 8704;
    for (int k = tid; k < KPAD; k += 256)
      clipw[c*KPAD + k] = (k < 588) ? f2bf(clip_w[c*588 + k]) : (u16)0;
    if (blk == 8704){
      for (int i = tid; i < BHW*4; i += 256) rowacc[i] = 0.f;
      if (tid == 0) *done = 0u;
    }
    return;
  }
  if (blk < 10880){
    const int r = blk - 9728;
    const int b = r / HW_, n = r % HW_;
    const int hi = n / 24, wi = n % 24;
    for (int p = tid; p < KPAD; p += 256){
      float v = 0.f;
      if (p < 588){
        int c3 = p / 196, rem = p - c3*196;
        int ph = rem / 14, pw = rem - ph*14;
        v = images[(((long)b*4 + c3)*336 + hi*14 + ph)*336 + wi*14 + pw];
      }
      patch[(long)r*KPAD + p] = f2bf(v);
    }
    return;
  }
  // gather (+ LayerNorm for g<7); image-token index computed inline (ids rows L2-resident)
  const int q = blk - 10880;
  const int r = q >> 3, g = q & 7;
  const int b = r / HW_, n = r % HW_;
  const int hi = n / 24, wi = n % 24;
  __shared__ int ridx[4];
  __shared__ float rs[4], rq[4];
  {
    int best = 0x7fffffff;
    for (int i = tid; i < NSEQ; i += 256)
      if (ids[b*NSEQ + i] == -200 && i < best) best = i;
    for (int off = 32; off; off >>= 1){ int o = __shfl_xor(best, off); best = min(best, o); }
    if ((tid & 63) == 0) ridx[tid >> 6] = best;
    __syncthreads();
  }
  const int tok = min(min(ridx[0],ridx[1]),min(ridx[2],ridx[3])) + 1 + hi*25 + wi;
  const int layer = (g < 7) ? (24 - g*4) : 24;
  const float* src = feats + (((long)(b*NSEQ + tok))*LL + layer)*DD + tid*8;
  float4 a = *(const float4*)src;
  float4 c = *(const float4*)(src + 4);
  if (g == 7){
    // raw layer-24 features -> fp8 (A8 slice 7), no LN
    uint2 o;
    o.x = pk4_fp8(a.x*ASCALE, a.y*ASCALE, a.z*ASCALE, a.w*ASCALE);
    o.y = pk4_fp8(c.x*ASCALE, c.y*ASCALE, c.z*ASCALE, c.w*ASCALE);
    *(uint2*)(A8 + (7L*BHW + r)*DD + tid*8) = o;
    return;
  }
  float s  = a.x+a.y+a.z+a.w + c.x+c.y+c.z+c.w;
  float qq = a.x*a.x+a.y*a.y+a.z*a.z+a.w*a.w + c.x*c.x+c.y*c.y+c.z*c.z+c.w*c.w;
  for (int off = 32; off; off >>= 1){ s += __shfl_xor(s, off); qq += __shfl_xor(qq, off); }
  const int wave = tid >> 6, lane = tid & 63;
  if (lane == 0){ rs[wave] = s; rq[wave] = qq; }
  __syncthreads();
  const float ts = rs[0]+rs[1]+rs[2]+rs[3];
  const float tq = rq[0]+rq[1]+rq[2]+rq[3];
  const float mu   = ts * (1.f/2048.f);
  const float var  = tq * (1.f/2048.f) - mu*mu;
  const float rstd = rsqrtf(var + 1e-5f);
  const float4 g0 = *(const float4*)(gamma + g*DD + tid*8);
  const float4 g1 = *(const float4*)(gamma + g*DD + tid*8 + 4);
  const float4 b0 = *(const float4*)(beta  + g*DD + tid*8);
  const float4 b1 = *(const float4*)(beta  + g*DD + tid*8 + 4);
  uint2 o;
  o.x = pk4_fp8(((a.x-mu)*rstd*g0.x + b0.x)*ASCALE, ((a.y-mu)*rstd*g0.y + b0.y)*ASCALE,
                ((a.z-mu)*rstd*g0.z + b0.z)*ASCALE, ((a.w-mu)*rstd*g0.w + b0.w)*ASCALE);
  o.y = pk4_fp8(((c.x-mu)*rstd*g1.x + b1.x)*ASCALE, ((c.y-mu)*rstd*g1.y + b1.y)*ASCALE,
                ((c.z-mu)*rstd*g1.z + b1.z)*ASCALE, ((c.w-mu)*rstd*g1.w + b1.w)*ASCALE);
  *(uint2*)(A8 + ((long)g*BHW + r)*DD + tid*8) = o;
}

// ---------- unified GEMM (launch 2 of 4): z=0..7 fp8 (7 vis + inp); z=8 clip bf16->fp32 ----------
// 1D grid of 648 blocks; flat%8 == z for z<8 so each XCD's L2 holds ONE z-slice
// (A8_z + B8_z ~ 4.3 MB vs 4 MiB L2; round-robin dispatch puts flat%8 on XCD flat%8).
// All 576 fp8 blocks are now uniform (no bf16 z=7 stragglers defining the tail).
__global__ __launch_bounds__(256, 3)
void gemm9_k(const u8* __restrict__ A8, const u8* __restrict__ B8,
             u16* __restrict__ C_all,
             const u16* __restrict__ patch, const u16* __restrict__ clipw,
             float* __restrict__ cf,
             const float* __restrict__ input_b, const float* __restrict__ clip_b){
  __shared__ alignas(16) u8 smem[32768];
  const int f = blockIdx.x;
  int z, t;
  if (f < 576){ z = f & 7; t = f >> 3; } else { z = 8; t = f - 576; }
  const int bm = (t % 9)*128, bn = (t / 9)*128;
  const int tid = threadIdx.x, wave = tid >> 6, lane = tid & 63;
  const int l15 = lane & 15, quad = lane >> 4;
  const int wr = (wave >> 1)*64, wc = (wave & 1)*64;
  f32x4 acc[4][4] = {};
  const int laneRow   = lane >> 3;
  const int laneChunk = (lane & 7) ^ laneRow;

  if (z < 8){
    // ---- MX-fp8, BK=128, XOR-16B-chunk swizzle, identity E8M0 scales ----
    u8* As = smem;
    u8* Bs = smem + 16384;
    const u8* Az = A8 + (long)z*BHW*DD;
    const u8* Bz = B8 + (long)z*CLIPC*DD;
    const u8* gA = Az + (long)(bm + wave*32 + laneRow)*DD + laneChunk*16;
    const u8* gB = Bz + (long)(bn + wave*32 + laneRow)*DD + laneChunk*16;
    u8* lA = &As[wave*32*128];
    u8* lB = &Bs[wave*32*128];
    const long rs8 = 8L*DD;
    for (int k0 = 0; k0 < DD; k0 += 128){
#pragma unroll
      for (int t2 = 0; t2 < 4; t2++) gld_lds16(gA + k0 + t2*rs8, lA + t2*1024);
#pragma unroll
      for (int t2 = 0; t2 < 4; t2++) gld_lds16(gB + k0 + t2*rs8, lB + t2*1024);
      __syncthreads();
      i32x8 af[4], bg[4];
      const int sw = l15 & 7;
#pragma unroll
      for (int i = 0; i < 4; i++){
        const u8* rp = &As[(wr + i*16 + l15)*128];
        uint4 lo = *(const uint4*)(rp + (((quad*2 + 0) ^ sw)*16));
        uint4 hi = *(const uint4*)(rp + (((quad*2 + 1) ^ sw)*16));
        af[i] = (i32x8){(int)lo.x,(int)lo.y,(int)lo.z,(int)lo.w,
                        (int)hi.x,(int)hi.y,(int)hi.z,(int)hi.w};
      }
#pragma unroll
      for (int j = 0; j < 4; j++){
        const u8* rp = &Bs[(wc + j*16 + l15)*128];
        uint4 lo = *(const uint4*)(rp + (((quad*2 + 0) ^ sw)*16));
        uint4 hi = *(const uint4*)(rp + (((quad*2 + 1) ^ sw)*16));
        bg[j] = (i32x8){(int)lo.x,(int)lo.y,(int)lo.z,(int)lo.w,
                        (int)hi.x,(int)hi.y,(int)hi.z,(int)hi.w};
      }
#pragma unroll
      for (int i = 0; i < 4; i++)
#pragma unroll
        for (int j = 0; j < 4; j++)
          acc[i][j] = __builtin_amdgcn_mfma_scale_f32_16x16x128_f8f6f4(
              af[i], bg[j], acc[i][j], 0, 0, 0, 0x7F7F7F7F, 0, 0x7F7F7F7F);
      __syncthreads();
    }
    u16* C = C_all + (long)z*BHW*CLIPC;
    if (z == 7){
#pragma unroll
      for (int i = 0; i < 4; i++)
#pragma unroll
        for (int j = 0; j < 4; j++)
#pragma unroll
          for (int rr = 0; rr < 4; rr++){
            const int row = bm + wr + i*16 + quad*4 + rr;
            const int col = bn + wc + j*16 + l15;
            C[(long)row*CLIPC + col] = f2bf(acc[i][j][rr] * INV_AB + input_b[col]);
          }
    } else {
#pragma unroll
      for (int i = 0; i < 4; i++)
#pragma unroll
        for (int j = 0; j < 4; j++)
#pragma unroll
          for (int rr = 0; rr < 4; rr++){
            const int row = bm + wr + i*16 + quad*4 + rr;
            const int col = bn + wc + j*16 + l15;
            C[(long)row*CLIPC + col] = f2bf(acc[i][j][rr] * INV_AB);
          }
    }
  } else {
    // ---- bf16 clip GEMM, BK=64, XOR swizzle -> cf (f32) ----
    u16* As = (u16*)smem;
    u16* Bs = (u16*)(smem + 16384);
    const int K = KPAD;
    const int laneCol = laneChunk * 8;
    const u16* gA = patch + (long)(bm + wave*32 + laneRow)*K + laneCol;
    const u16* gB = clipw + (long)(bn + wave*32 + laneRow)*K + laneCol;
    u16* lA = &As[wave*2048];
    u16* lB = &Bs[wave*2048];
    const long rs8 = (long)8 * K;
    for (int k0 = 0; k0 < K; k0 += 64){
#pragma unroll
      for (int t2 = 0; t2 < 4; t2++) gld_lds16(gA + k0 + t2*rs8, lA + t2*512);
#pragma unroll
      for (int t2 = 0; t2 < 4; t2++) gld_lds16(gB + k0 + t2*rs8, lB + t2*512);
      __syncthreads();
#pragma unroll
      for (int s = 0; s < 2; s++){
        bf16x8 af[4], bg[4];
#pragma unroll
        for (int i = 0; i < 4; i++)
          af[i] = *(const bf16x8*)&As[(wr + i*16 + l15)*64 + (((s*4 + quad) ^ (l15 & 7))*8)];
#pragma unroll
        for (int j = 0; j < 4; j++)
          bg[j] = *(const bf16x8*)&Bs[(wc + j*16 + l15)*64 + (((s*4 + quad) ^ (l15 & 7))*8)];
#pragma unroll
        for (int i = 0; i < 4; i++)
#pragma unroll
          for (int j = 0; j < 4; j++)
            acc[i][j] = __builtin_amdgcn_mfma_f32_16x16x32_bf16(af[i], bg[j], acc[i][j], 0, 0, 0);
      }
      __syncthreads();
    }
#pragma unroll
    for (int i = 0; i < 4; i++)
#pragma unroll
      for (int j = 0; j < 4; j++)
#pragma unroll
        for (int rr = 0; rr < 4; rr++){
          const int row = bm + wr + i*16 + quad*4 + rr;
          const int col = bn + wc + j*16 + l15;
          cf[(long)row*CLIPC + col] = acc[i][j][rr] + clip_b[col];
        }
  }
}

// ---------- attention (launch 3 of 4): 256 threads = 4 heads ----------
__global__ void attn_k(const u16* __restrict__ C_all, u16* __restrict__ fuse){
  const int r = blockIdx.x;
  const int h = (blockIdx.y << 2) | (threadIdx.x >> 6);
  const int lane = threadIdx.x & 63;
  const long slot = (long)BHW * CLIPC;
  const long rb = (long)r * CLIPC;
  const int c0 = h*128 + lane, c1 = c0 + 64;
  const float q0 = bf2f(C_all[rb + c0]), q1 = bf2f(C_all[rb + c1]);
  float k0v[6], k1v[6], dt[6];
#pragma unroll
  for (int t = 0; t < 6; t++){
    const u16* base = C_all + (long)(t+1)*slot + rb;
    k0v[t] = bf2f(base[c0]); k1v[t] = bf2f(base[c1]);
    dt[t] = q0*k0v[t] + q1*k1v[t];
  }
#pragma unroll
  for (int t = 0; t < 6; t++)
    for (int off = 32; off; off >>= 1) dt[t] += __shfl_xor(dt[t], off);
  float l[6], e[6];
#pragma unroll
  for (int t = 0; t < 6; t++) l[t] = dt[t] * 0.03125f;
  float m = l[0];
#pragma unroll
  for (int t = 1; t < 6; t++) m = fmaxf(m, l[t]);
  float ssum = 0.f;
#pragma unroll
  for (int t = 0; t < 6; t++){ e[t] = __expf(l[t] - m); ssum += e[t]; }
  const float inv = 1.f / ssum;
  float f0 = 0.f, f1 = 0.f;
#pragma unroll
  for (int t = 0; t < 6; t++){ const float a = e[t]*inv; f0 += a*k0v[t]; f1 += a*k1v[t]; }
  fuse[rb + c0] = f2bf(f0);
  fuse[rb + c1] = f2bf(f1);
}

// ---------- output GEMM + cosine partials + last-block final loss (launch 4 of 4) ----------
// Only 72 blocks -> 1 block/CU -> no cross-block TLP to hide staging latency.
// Double-buffered LDS (64 KB): issue next K-chunk's global_load_lds BEFORE computing
// the current one; __syncthreads' vmcnt(0) drain then overlaps the MFMA phase.
__global__ __launch_bounds__(256, 2)
void gemm_out_k(const u16* __restrict__ fuse, const u16* __restrict__ outw,
                const u16* __restrict__ inp, const float* __restrict__ output_b,
                const float* __restrict__ cf, float* __restrict__ rowacc,
                unsigned int* __restrict__ done, float* __restrict__ out){
  __shared__ alignas(16) u8 smem[65536];
  const int bm = blockIdx.x*128, bn = blockIdx.y*128;
  const int tid = threadIdx.x, wave = tid >> 6, lane = tid & 63;
  const int l15 = lane & 15, quad = lane >> 4;
  const int wr = (wave >> 1)*64, wc = (wave & 1)*64;
  f32x4 acc[4][4] = {};
  {
    const int laneRow = lane >> 3;
    const int laneCol = (((lane & 7) ^ laneRow) * 8);
    const u16* gA = fuse + (long)(bm + wave*32 + laneRow)*CLIPC + laneCol;
    const u16* gB = outw + (long)(bn + wave*32 + laneRow)*CLIPC + laneCol;
    const long rs8 = 8L*CLIPC;
    // prologue: stage k0=0 into buffer 0
#pragma unroll
    for (int t = 0; t < 4; t++) gld_lds16(gA + t*rs8, (u16*)smem + wave*2048 + t*512);
#pragma unroll
    for (int t = 0; t < 4; t++) gld_lds16(gB + t*rs8, (u16*)(smem + 16384) + wave*2048 + t*512);
    __syncthreads();
    for (int k0 = 0; k0 < CLIPC; k0 += 64){
      const int cur = (k0 >> 6) & 1;
      if (k0 + 64 < CLIPC){
        u16* lA = (u16*)(smem + (cur^1)*32768)         + wave*2048;
        u16* lB = (u16*)(smem + (cur^1)*32768 + 16384) + wave*2048;
#pragma unroll
        for (int t = 0; t < 4; t++) gld_lds16(gA + (k0+64) + t*rs8, lA + t*512);
#pragma unroll
        for (int t = 0; t < 4; t++) gld_lds16(gB + (k0+64) + t*rs8, lB + t*512);
      }
      const u16* As = (const u16*)(smem + cur*32768);
      const u16* Bs = (const u16*)(smem + cur*32768 + 16384);
#pragma unroll
      for (int s = 0; s < 2; s++){
        bf16x8 af[4], bg[4];
#pragma unroll
        for (int i = 0; i < 4; i++)
          af[i] = *(const bf16x8*)&As[(wr + i*16 + l15)*64 + (((s*4 + quad) ^ (l15 & 7))*8)];
#pragma unroll
        for (int j = 0; j < 4; j++)
          bg[j] = *(const bf16x8*)&Bs[(wc + j*16 + l15)*64 + (((s*4 + quad) ^ (l15 & 7))*8)];
#pragma unroll
        for (int i = 0; i < 4; i++)
#pragma unroll
          for (int j = 0; j < 4; j++)
            acc[i][j] = __builtin_amdgcn_mfma_f32_16x16x32_bf16(af[i], bg[j], acc[i][j], 0, 0, 0);
      }
      __syncthreads();   // drains vmcnt(0): next buffer's staging completes under this iter's MFMAs
    }
  }
#pragma unroll
  for (int i = 0; i < 4; i++)
#pragma unroll
    for (int rr = 0; rr < 4; rr++){
      const int row = bm + wr + i*16 + quad*4 + rr;
      float soc = 0.f, soo = 0.f, scc = 0.f;
#pragma unroll
      for (int j = 0; j < 4; j++){
        const int col = bn + wc + j*16 + l15;
        const long p = (long)row*CLIPC + col;
        const float o = acc[i][j][rr] + output_b[col] + bf2f(inp[p]);
        const float c = cf[p];
        soc += o*c; soo += o*o; scc += c*c;
      }
#pragma unroll
      for (int off = 1; off < 16; off <<= 1){
        soc += __shfl_xor(soc, off); soo += __shfl_xor(soo, off); scc += __shfl_xor(scc, off);
      }
      if (l15 == 0){
        atomicAdd(&rowacc[row*4 + 0], soc);
        atomicAdd(&rowacc[row*4 + 1], soo);
        atomicAdd(&rowacc[row*4 + 2], scc);
      }
    }
  // ---- last block computes the final loss ----
  __threadfence();
  __shared__ unsigned int amLast;
  if (tid == 0) amLast = (atomicAdd(done, 1u) == 71u) ? 1u : 0u;
  __syncthreads();
  if (!amLast) return;
  float s = 0.f;
  for (int r = tid; r < BHW; r += 256){
    const float soc = __hip_atomic_load(&rowacc[r*4+0], __ATOMIC_RELAXED, __HIP_MEMORY_SCOPE_AGENT);
    const float soo = __hip_atomic_load(&rowacc[r*4+1], __ATOMIC_RELAXED, __HIP_MEMORY_SCOPE_AGENT);
    const float scc = __hip_atomic_load(&rowacc[r*4+2], __ATOMIC_RELAXED, __HIP_MEMORY_SCOPE_AGENT);
    s += soc / fmaxf(sqrtf(soo*scc), 1e-8f);
  }
  for (int off = 32; off; off >>= 1) s += __shfl_xor(s, off);
  __shared__ float fr[4];
  if ((tid & 63) == 0) fr[tid >> 6] = s;
  __syncthreads();
  if (tid == 0) out[0] = 1.f - (fr[0]+fr[1]+fr[2]+fr[3]) * (1.f/(float)BHW);
}

extern "C" void kernel_launch(void* const* d_in, const int* in_sizes, int n_in,
                              void* d_out, int out_size, void* d_ws, size_t ws_size,
                              hipStream_t stream){
  const int*   input_ids = (const int*)  d_in[0];
  const float* images    = (const float*)d_in[1];
  const float* all_feats = (const float*)d_in[2];
  const float* norm_gamma = (const float*)d_in[4];
  const float* norm_beta  = (const float*)d_in[5];
  const float* norm_w     = (const float*)d_in[6];
  const float* input_w    = (const float*)d_in[7];
  const float* input_b    = (const float*)d_in[8];
  const float* output_w   = (const float*)d_in[9];
  const float* output_b   = (const float*)d_in[10];
  const float* clip_w     = (const float*)d_in[11];
  const float* clip_b     = (const float*)d_in[12];
  float* out = (float*)d_out;

  // ---- workspace layout (~75 MB) ----
  char* w = (char*)d_ws;
  unsigned int* done = (unsigned int*)w;
  size_t off = 256;
  u8*  A8    = (u8*) (w + off); off += 8L*BHW*DD;
  u8*  B8    = (u8*) (w + off); off += 8L*CLIPC*DD;
  u16* outw  = (u16*)(w + off); off += (long)CLIPC*CLIPC*2;
  u16* clipw = (u16*)(w + off); off += (long)CLIPC*KPAD*2;
  u16* patch = (u16*)(w + off); off += (long)BHW*KPAD*2;
  u16* C_all = (u16*)(w + off); off += 8L*BHW*CLIPC*2;
  u16* fuse  = (u16*)(w + off); off += (long)BHW*CLIPC*2;
  float* cf     = (float*)(w + off); off += (long)BHW*CLIPC*4;
  float* rowacc = (float*)(w + off); off += (long)BHW*4*4;

  prep_k<<<20096, 256, 0, stream>>>(norm_w, input_w, output_w, clip_w, images, all_feats,
                                    input_ids, norm_gamma, norm_beta,
                                    B8, outw, clipw, patch, A8, rowacc, done);
  gemm9_k<<<648, 256, 0, stream>>>(A8, B8, C_all, patch, clipw, cf,
                                   input_b, clip_b);
  attn_k<<<dim3(1152, 2), 256, 0, stream>>>(C_all, fuse);
  gemm_out_k<<<dim3(9, 8), 256, 0, stream>>>(fuse, outw, C_all + 7L*BHW*CLIPC,
                                             output_b, cf, rowacc, done, out);
}